// Round 1
// baseline (971.547 us; speedup 1.0000x reference)
//
#include <hip/hip_runtime.h>
#include <hip/hip_bf16.h>
#include <cstdint>

#define DD 8192
#define NROW 200
#define MT 13          // 13 M-tiles of 16 rows = 208
#define MPAD 208
#define KPV 256        // padded K for the PV GEMM
#define EPSV 1e-5f

using short8 = __attribute__((ext_vector_type(8))) short;
using f32x4  = __attribute__((ext_vector_type(4))) float;

__device__ __forceinline__ ushort f2bf(float f) {
    union { float f; unsigned u; } c; c.f = f;
    unsigned u = c.u;
    return (ushort)((u + 0x7FFFu + ((u >> 16) & 1u)) >> 16);  // RNE
}

// ---------------- kernel 1: x (f32 [200][8192]) -> xb (bf16 [208][8192], pad rows 0)
__global__ void cvt_x(const float* __restrict__ x, ushort* __restrict__ xb) {
    int i = (blockIdx.x * 256 + threadIdx.x) * 8;   // element index in [0, 208*8192)
    int row = i >> 13;
    int col = i & (DD - 1);
    short8 o;
    if (row < NROW) {
        const float4* p = reinterpret_cast<const float4*>(x + (size_t)row * DD + col);
        float4 a = p[0], b = p[1];
        o[0]=f2bf(a.x); o[1]=f2bf(a.y); o[2]=f2bf(a.z); o[3]=f2bf(a.w);
        o[4]=f2bf(b.x); o[5]=f2bf(b.y); o[6]=f2bf(b.z); o[7]=f2bf(b.w);
    } else {
        for (int j = 0; j < 8; ++j) o[j] = 0;
    }
    *reinterpret_cast<short8*>(xb + i) = o;
}

// ---------------- kernel 2: fused QKV GEMM.  C = x @ W^T + b
// grid (8192/64, 3), block 256 (4 waves). Wave w owns cols [bx*64 + w*16, +16), all 13 M-tiles.
__global__ __launch_bounds__(256) void qkv_gemm(
    const ushort* __restrict__ xb,
    const float* __restrict__ Wq, const float* __restrict__ Wk, const float* __restrict__ Wv,
    const float* __restrict__ bq, const float* __restrict__ bk, const float* __restrict__ bv,
    ushort* __restrict__ qb, ushort* __restrict__ kb, float* __restrict__ vf)
{
    const int mat = blockIdx.y;
    const float* W    = (mat == 0) ? Wq : (mat == 1 ? Wk : Wv);
    const float* bias = (mat == 0) ? bq : (mat == 1 ? bk : bv);

    const int lane  = threadIdx.x & 63;
    const int wave  = threadIdx.x >> 6;
    const int col16 = lane & 15;
    const int kgrp  = lane >> 4;
    const int ncol  = blockIdx.x * 64 + wave * 16 + col16;

    const float*  wp  = W  + (size_t)ncol * DD + kgrp * 8;
    const ushort* ap0 = xb + (size_t)col16 * DD + kgrp * 8;

    f32x4 acc[MT];
    for (int m = 0; m < MT; ++m)
        for (int r = 0; r < 4; ++r) acc[m][r] = 0.f;

    for (int k0 = 0; k0 < DD; k0 += 32) {
        float4 w0 = *reinterpret_cast<const float4*>(wp + k0);
        float4 w1 = *reinterpret_cast<const float4*>(wp + k0 + 4);
        short8 b;
        b[0]=f2bf(w0.x); b[1]=f2bf(w0.y); b[2]=f2bf(w0.z); b[3]=f2bf(w0.w);
        b[4]=f2bf(w1.x); b[5]=f2bf(w1.y); b[6]=f2bf(w1.z); b[7]=f2bf(w1.w);
        #pragma unroll
        for (int m = 0; m < MT; ++m) {
            short8 a = *reinterpret_cast<const short8*>(ap0 + (size_t)m * 16 * DD + k0);
            acc[m] = __builtin_amdgcn_mfma_f32_16x16x32_bf16(a, b, acc[m], 0, 0, 0);
        }
    }

    const float badd = bias[ncol];
    if (mat < 2) {
        ushort* outb = (mat == 0) ? qb : kb;
        for (int m = 0; m < MT; ++m)
            for (int r = 0; r < 4; ++r) {
                int row = m * 16 + kgrp * 4 + r;           // C/D: col=lane&15, row=(lane>>4)*4+r
                outb[(size_t)row * DD + ncol] = f2bf(acc[m][r] + badd);
            }
    } else {
        for (int m = 0; m < MT; ++m)
            for (int r = 0; r < 4; ++r) {
                int row = m * 16 + kgrp * 4 + r;
                if (row < NROW) vf[(size_t)row * DD + ncol] = acc[m][r] + badd;
            }
    }
}

// ---------------- kernel 3: v (f32 [200][8192]) -> vt (bf16 [8192][256]), vt[n][k] = v[k][n], k>=200 -> 0
__global__ void vtrans(const float* __restrict__ vf, ushort* __restrict__ vt) {
    __shared__ float lds[64][65];
    const int t  = threadIdx.x;
    const int n0 = blockIdx.x * 64;
    const int k0 = blockIdx.y * 64;
    #pragma unroll
    for (int r = 0; r < 16; ++r) {
        int kl = r * 4 + (t >> 6);
        int nl = t & 63;
        int k  = k0 + kl;
        lds[nl][kl] = (k < NROW) ? vf[(size_t)k * DD + n0 + nl] : 0.f;
    }
    __syncthreads();
    int nl   = t >> 2;
    int koff = (t & 3) * 16;
    short8 o0, o1;
    for (int j = 0; j < 8; ++j) { o0[j] = f2bf(lds[nl][koff + j]); o1[j] = f2bf(lds[nl][koff + 8 + j]); }
    short8* dst = reinterpret_cast<short8*>(vt + (size_t)(n0 + nl) * KPV + k0 + koff);
    dst[0] = o0; dst[1] = o1;
}

// ---------------- kernel 4: s = q @ k^T  (f32 [208][208]); grid (13,13), 4-wave K-split
__global__ __launch_bounds__(256) void sgemm(const ushort* __restrict__ qb, const ushort* __restrict__ kb,
                                             float* __restrict__ sbuf) {
    const int bm = blockIdx.y, bn = blockIdx.x;
    const int lane  = threadIdx.x & 63;
    const int wave  = threadIdx.x >> 6;
    const int col16 = lane & 15, kgrp = lane >> 4;
    const ushort* ap = qb + (size_t)(bm * 16 + col16) * DD + kgrp * 8;
    const ushort* bp = kb + (size_t)(bn * 16 + col16) * DD + kgrp * 8;
    f32x4 acc;
    for (int r = 0; r < 4; ++r) acc[r] = 0.f;
    const int kend = (wave + 1) * 2048;
    for (int k0 = wave * 2048; k0 < kend; k0 += 32) {
        short8 a = *reinterpret_cast<const short8*>(ap + k0);
        short8 b = *reinterpret_cast<const short8*>(bp + k0);
        acc = __builtin_amdgcn_mfma_f32_16x16x32_bf16(a, b, acc, 0, 0, 0);
    }
    __shared__ f32x4 red[4][64];
    red[wave][lane] = acc;
    __syncthreads();
    if (wave == 0) {
        f32x4 s = red[0][lane];
        for (int j = 1; j < 4; ++j) { f32x4 o = red[j][lane]; for (int r = 0; r < 4; ++r) s[r] += o[r]; }
        for (int r = 0; r < 4; ++r)
            sbuf[(size_t)(bm * 16 + kgrp * 4 + r) * MPAD + bn * 16 + col16] = s[r];
    }
}

// ---------------- kernel 5: per-row mean/var(ddof=1) -> sin -> softmax -> P bf16 [208][256] (pads 0)
__global__ __launch_bounds__(256) void rownorm(const float* __restrict__ sbuf, ushort* __restrict__ pb) {
    const int row = blockIdx.x;
    const int t = threadIdx.x;
    if (row >= NROW) { pb[(size_t)row * KPV + t] = 0; return; }
    __shared__ float part[4];
    const int lane = t & 63, wave = t >> 6;
    float x = (t < NROW) ? sbuf[(size_t)row * MPAD + t] : 0.f;

    float s = x;
    for (int m = 32; m; m >>= 1) s += __shfl_xor(s, m, 64);
    if (lane == 0) part[wave] = s;
    __syncthreads();
    float mean = (part[0] + part[1] + part[2] + part[3]) * (1.f / 200.f);

    float d = (t < NROW) ? (x - mean) : 0.f;
    float s2 = d * d;
    for (int m = 32; m; m >>= 1) s2 += __shfl_xor(s2, m, 64);
    __syncthreads();
    if (lane == 0) part[wave] = s2;
    __syncthreads();
    float var = (part[0] + part[1] + part[2] + part[3]) * (1.f / 199.f);

    float inv = 1.f / sqrtf(var + EPSV);
    float y = sinf(d * inv);
    const float inv_cc = 1.f / 90.50966799187809f;   // 1/sqrt(8192)
    float e = (t < NROW) ? expf(y * inv_cc) : 0.f;

    float se = e;
    for (int m = 32; m; m >>= 1) se += __shfl_xor(se, m, 64);
    __syncthreads();
    if (lane == 0) part[wave] = se;
    __syncthreads();
    float tot = part[0] + part[1] + part[2] + part[3];
    pb[(size_t)row * KPV + t] = (t < NROW) ? f2bf(e / tot) : (ushort)0;
}

// ---------------- kernel 6: out = P @ V  via out[m][n] = sum_k P[m][k] * vt[n][k]
__global__ __launch_bounds__(256) void pv_gemm(const ushort* __restrict__ pb, const ushort* __restrict__ vt,
                                               float* __restrict__ out) {
    const int lane  = threadIdx.x & 63;
    const int wave  = threadIdx.x >> 6;
    const int col16 = lane & 15, kgrp = lane >> 4;
    const int ncol  = blockIdx.x * 64 + wave * 16 + col16;
    const ushort* ap = pb + (size_t)col16 * KPV + kgrp * 8;
    const ushort* bp = vt + (size_t)ncol  * KPV + kgrp * 8;
    f32x4 acc[MT];
    for (int m = 0; m < MT; ++m)
        for (int r = 0; r < 4; ++r) acc[m][r] = 0.f;
    for (int k0 = 0; k0 < KPV; k0 += 32) {
        short8 b = *reinterpret_cast<const short8*>(bp + k0);
        #pragma unroll
        for (int m = 0; m < MT; ++m) {
            short8 a = *reinterpret_cast<const short8*>(ap + (size_t)m * 16 * KPV + k0);
            acc[m] = __builtin_amdgcn_mfma_f32_16x16x32_bf16(a, b, acc[m], 0, 0, 0);
        }
    }
    for (int m = 0; m < MT; ++m)
        for (int r = 0; r < 4; ++r) {
            int row = m * 16 + kgrp * 4 + r;
            if (row < NROW) out[(size_t)row * DD + ncol] = acc[m][r];
        }
}

extern "C" void kernel_launch(void* const* d_in, const int* in_sizes, int n_in,
                              void* d_out, int out_size, void* d_ws, size_t ws_size,
                              hipStream_t stream) {
    const float* x  = (const float*)d_in[0];
    const float* Wq = (const float*)d_in[1];
    const float* bq = (const float*)d_in[2];
    const float* Wk = (const float*)d_in[3];
    const float* bk = (const float*)d_in[4];
    const float* Wv = (const float*)d_in[5];
    const float* bv = (const float*)d_in[6];
    float* out = (float*)d_out;

    char* ws = (char*)d_ws;
    ushort* xb   = (ushort*)(ws);                       // 208*8192*2 = 3,407,872
    ushort* qb   = (ushort*)(ws + 3407872);             // 3,407,872
    ushort* kb   = (ushort*)(ws + 6815744);             // 3,407,872
    float*  vf   = (float*)(ws + 10223616);             // 200*8192*4 = 6,553,600
    ushort* vt   = (ushort*)(ws + 16777216);            // 8192*256*2 = 4,194,304
    float*  sbuf = (float*)(ws + 20971520);             // 208*208*4 = 173,056
    ushort* pb   = (ushort*)(ws + 21144576);            // 208*256*2 = 106,496
    // total 21,251,072 bytes

    cvt_x<<<832, 256, 0, stream>>>(x, xb);
    qkv_gemm<<<dim3(128, 3), 256, 0, stream>>>(xb, Wq, Wk, Wv, bq, bk, bv, qb, kb, vf);
    vtrans<<<dim3(128, 4), 256, 0, stream>>>(vf, vt);
    sgemm<<<dim3(13, 13), 256, 0, stream>>>(qb, kb, sbuf);
    rownorm<<<208, 256, 0, stream>>>(sbuf, pb);
    pv_gemm<<<128, 256, 0, stream>>>(pb, vt, out);
}

// Round 2
// 853.765 us; speedup vs baseline: 1.1380x; 1.1380x over previous
//
#include <hip/hip_runtime.h>
#include <hip/hip_bf16.h>
#include <cstdint>

#define DD 8192
#define NROW 200
#define MT 13          // 13 M-tiles of 16 rows = 208
#define MPAD 208
#define KPV 256        // padded K for the PV GEMM
#define EPSV 1e-5f

using short8 = __attribute__((ext_vector_type(8))) short;
using f32x4  = __attribute__((ext_vector_type(4))) float;

__device__ __forceinline__ ushort f2bf(float f) {
    union { float f; unsigned u; } c; c.f = f;
    unsigned u = c.u;
    return (ushort)((u + 0x7FFFu + ((u >> 16) & 1u)) >> 16);  // RNE
}

__device__ __forceinline__ short8 pack8(float4 a, float4 b) {
    short8 o;
    o[0]=f2bf(a.x); o[1]=f2bf(a.y); o[2]=f2bf(a.z); o[3]=f2bf(a.w);
    o[4]=f2bf(b.x); o[5]=f2bf(b.y); o[6]=f2bf(b.z); o[7]=f2bf(b.w);
    return o;
}

// ---------------- kernel 1: x (f32 [200][8192]) -> xb (bf16 [208][8192], pad rows 0)
__global__ void cvt_x(const float* __restrict__ x, ushort* __restrict__ xb) {
    int i = (blockIdx.x * 256 + threadIdx.x) * 8;
    int row = i >> 13;
    int col = i & (DD - 1);
    short8 o;
    if (row < NROW) {
        const float4* p = reinterpret_cast<const float4*>(x + (size_t)row * DD + col);
        float4 a = p[0], b = p[1];
        o = pack8(a, b);
    } else {
        for (int j = 0; j < 8; ++j) o[j] = 0;
    }
    *reinterpret_cast<short8*>(xb + i) = o;
}

// ---------------- kernel 2: fused QKV GEMM.  C = x @ W^T + b
// grid (512, 3), block 64 (1 wave). Each wave owns 16 output cols, all 13 M-tiles.
// 2-chunk-deep register prefetch of W (8 dwordx4 in flight across the MFMA block).
__global__ __launch_bounds__(64) void qkv_gemm(
    const ushort* __restrict__ xb,
    const float* __restrict__ Wq, const float* __restrict__ Wk, const float* __restrict__ Wv,
    const float* __restrict__ bq, const float* __restrict__ bk, const float* __restrict__ bv,
    ushort* __restrict__ qb, ushort* __restrict__ kb, float* __restrict__ vf)
{
    const int mat = blockIdx.y;
    const float* W    = (mat == 0) ? Wq : (mat == 1 ? Wk : Wv);
    const float* bias = (mat == 0) ? bq : (mat == 1 ? bk : bv);

    const int lane  = threadIdx.x;      // 0..63
    const int col16 = lane & 15;
    const int kgrp  = lane >> 4;
    const int ncol  = blockIdx.x * 16 + col16;

    const float*  wp  = W  + (size_t)ncol * DD + kgrp * 8;
    const ushort* ap0 = xb + (size_t)col16 * DD + kgrp * 8;

    f32x4 acc[MT];
    #pragma unroll
    for (int m = 0; m < MT; ++m)
        for (int r = 0; r < 4; ++r) acc[m][r] = 0.f;

    // prologue: prefetch chunks 0 (fA: k 0..63) and 1 (fB: k 64..127)
    float4 fA0 = *reinterpret_cast<const float4*>(wp + 0);
    float4 fA1 = *reinterpret_cast<const float4*>(wp + 4);
    float4 fA2 = *reinterpret_cast<const float4*>(wp + 32);
    float4 fA3 = *reinterpret_cast<const float4*>(wp + 36);
    float4 fB0 = *reinterpret_cast<const float4*>(wp + 64);
    float4 fB1 = *reinterpret_cast<const float4*>(wp + 68);
    float4 fB2 = *reinterpret_cast<const float4*>(wp + 96);
    float4 fB3 = *reinterpret_cast<const float4*>(wp + 100);

    for (int k0 = 0; k0 < DD; k0 += 128) {
        // ---- even 64-k chunk: consume fA (k0..k0+63), prefetch k0+128 into fA
        short8 b0 = pack8(fA0, fA1);
        short8 b1 = pack8(fA2, fA3);
        {
            int kp = (k0 + 128) & (DD - 1);   // wrap keeps tail loads in-bounds (dead data)
            fA0 = *reinterpret_cast<const float4*>(wp + kp);
            fA1 = *reinterpret_cast<const float4*>(wp + kp + 4);
            fA2 = *reinterpret_cast<const float4*>(wp + kp + 32);
            fA3 = *reinterpret_cast<const float4*>(wp + kp + 36);
        }
        #pragma unroll
        for (int m = 0; m < MT; ++m) {
            short8 a = *reinterpret_cast<const short8*>(ap0 + (size_t)m * 16 * DD + k0);
            acc[m] = __builtin_amdgcn_mfma_f32_16x16x32_bf16(a, b0, acc[m], 0, 0, 0);
        }
        #pragma unroll
        for (int m = 0; m < MT; ++m) {
            short8 a = *reinterpret_cast<const short8*>(ap0 + (size_t)m * 16 * DD + k0 + 32);
            acc[m] = __builtin_amdgcn_mfma_f32_16x16x32_bf16(a, b1, acc[m], 0, 0, 0);
        }

        // ---- odd 64-k chunk: consume fB (k0+64..k0+127), prefetch k0+192 into fB
        short8 c0 = pack8(fB0, fB1);
        short8 c1 = pack8(fB2, fB3);
        {
            int kp = (k0 + 192) & (DD - 1);
            fB0 = *reinterpret_cast<const float4*>(wp + kp);
            fB1 = *reinterpret_cast<const float4*>(wp + kp + 4);
            fB2 = *reinterpret_cast<const float4*>(wp + kp + 32);
            fB3 = *reinterpret_cast<const float4*>(wp + kp + 36);
        }
        #pragma unroll
        for (int m = 0; m < MT; ++m) {
            short8 a = *reinterpret_cast<const short8*>(ap0 + (size_t)m * 16 * DD + k0 + 64);
            acc[m] = __builtin_amdgcn_mfma_f32_16x16x32_bf16(a, c0, acc[m], 0, 0, 0);
        }
        #pragma unroll
        for (int m = 0; m < MT; ++m) {
            short8 a = *reinterpret_cast<const short8*>(ap0 + (size_t)m * 16 * DD + k0 + 96);
            acc[m] = __builtin_amdgcn_mfma_f32_16x16x32_bf16(a, c1, acc[m], 0, 0, 0);
        }
    }

    const float badd = bias[ncol];
    if (mat < 2) {
        ushort* outb = (mat == 0) ? qb : kb;
        for (int m = 0; m < MT; ++m)
            for (int r = 0; r < 4; ++r) {
                int row = m * 16 + kgrp * 4 + r;           // C/D: col=lane&15, row=(lane>>4)*4+r
                outb[(size_t)row * DD + ncol] = f2bf(acc[m][r] + badd);
            }
    } else {
        for (int m = 0; m < MT; ++m)
            for (int r = 0; r < 4; ++r) {
                int row = m * 16 + kgrp * 4 + r;
                if (row < NROW) vf[(size_t)row * DD + ncol] = acc[m][r] + badd;
            }
    }
}

// ---------------- kernel 3: v (f32 [200][8192]) -> vt (bf16 [8192][256]), vt[n][k] = v[k][n], k>=200 -> 0
__global__ void vtrans(const float* __restrict__ vf, ushort* __restrict__ vt) {
    __shared__ float lds[64][65];
    const int t  = threadIdx.x;
    const int n0 = blockIdx.x * 64;
    const int k0 = blockIdx.y * 64;
    #pragma unroll
    for (int r = 0; r < 16; ++r) {
        int kl = r * 4 + (t >> 6);
        int nl = t & 63;
        int k  = k0 + kl;
        lds[nl][kl] = (k < NROW) ? vf[(size_t)k * DD + n0 + nl] : 0.f;
    }
    __syncthreads();
    int nl   = t >> 2;
    int koff = (t & 3) * 16;
    short8 o0, o1;
    for (int j = 0; j < 8; ++j) { o0[j] = f2bf(lds[nl][koff + j]); o1[j] = f2bf(lds[nl][koff + 8 + j]); }
    short8* dst = reinterpret_cast<short8*>(vt + (size_t)(n0 + nl) * KPV + k0 + koff);
    dst[0] = o0; dst[1] = o1;
}

// ---------------- kernel 4: s = q @ k^T  (f32 [208][208]); grid (13,13), 4-wave K-split
__global__ __launch_bounds__(256) void sgemm(const ushort* __restrict__ qb, const ushort* __restrict__ kb,
                                             float* __restrict__ sbuf) {
    const int bm = blockIdx.y, bn = blockIdx.x;
    const int lane  = threadIdx.x & 63;
    const int wave  = threadIdx.x >> 6;
    const int col16 = lane & 15, kgrp = lane >> 4;
    const ushort* ap = qb + (size_t)(bm * 16 + col16) * DD + kgrp * 8;
    const ushort* bp = kb + (size_t)(bn * 16 + col16) * DD + kgrp * 8;
    f32x4 acc;
    for (int r = 0; r < 4; ++r) acc[r] = 0.f;
    const int kend = (wave + 1) * 2048;
    for (int k0 = wave * 2048; k0 < kend; k0 += 32) {
        short8 a = *reinterpret_cast<const short8*>(ap + k0);
        short8 b = *reinterpret_cast<const short8*>(bp + k0);
        acc = __builtin_amdgcn_mfma_f32_16x16x32_bf16(a, b, acc, 0, 0, 0);
    }
    __shared__ f32x4 red[4][64];
    red[wave][lane] = acc;
    __syncthreads();
    if (wave == 0) {
        f32x4 s = red[0][lane];
        for (int j = 1; j < 4; ++j) { f32x4 o = red[j][lane]; for (int r = 0; r < 4; ++r) s[r] += o[r]; }
        for (int r = 0; r < 4; ++r)
            sbuf[(size_t)(bm * 16 + kgrp * 4 + r) * MPAD + bn * 16 + col16] = s[r];
    }
}

// ---------------- kernel 5: per-row mean/var(ddof=1) -> sin -> softmax -> P bf16 [208][256] (pads 0)
__global__ __launch_bounds__(256) void rownorm(const float* __restrict__ sbuf, ushort* __restrict__ pb) {
    const int row = blockIdx.x;
    const int t = threadIdx.x;
    if (row >= NROW) { pb[(size_t)row * KPV + t] = 0; return; }
    __shared__ float part[4];
    const int lane = t & 63, wave = t >> 6;
    float x = (t < NROW) ? sbuf[(size_t)row * MPAD + t] : 0.f;

    float s = x;
    for (int m = 32; m; m >>= 1) s += __shfl_xor(s, m, 64);
    if (lane == 0) part[wave] = s;
    __syncthreads();
    float mean = (part[0] + part[1] + part[2] + part[3]) * (1.f / 200.f);

    float d = (t < NROW) ? (x - mean) : 0.f;
    float s2 = d * d;
    for (int m = 32; m; m >>= 1) s2 += __shfl_xor(s2, m, 64);
    __syncthreads();
    if (lane == 0) part[wave] = s2;
    __syncthreads();
    float var = (part[0] + part[1] + part[2] + part[3]) * (1.f / 199.f);

    float inv = 1.f / sqrtf(var + EPSV);
    float y = sinf(d * inv);
    const float inv_cc = 1.f / 90.50966799187809f;   // 1/sqrt(8192)
    float e = (t < NROW) ? expf(y * inv_cc) : 0.f;

    float se = e;
    for (int m = 32; m; m >>= 1) se += __shfl_xor(se, m, 64);
    __syncthreads();
    if (lane == 0) part[wave] = se;
    __syncthreads();
    float tot = part[0] + part[1] + part[2] + part[3];
    pb[(size_t)row * KPV + t] = (t < NROW) ? f2bf(e / tot) : (ushort)0;
}

// ---------------- kernel 6: out = P @ V  via out[m][n] = sum_k P[m][k] * vt[n][k]
__global__ __launch_bounds__(256) void pv_gemm(const ushort* __restrict__ pb, const ushort* __restrict__ vt,
                                               float* __restrict__ out) {
    const int lane  = threadIdx.x & 63;
    const int wave  = threadIdx.x >> 6;
    const int col16 = lane & 15, kgrp = lane >> 4;
    const int ncol  = blockIdx.x * 64 + wave * 16 + col16;
    const ushort* ap = pb + (size_t)col16 * KPV + kgrp * 8;
    const ushort* bp = vt + (size_t)ncol  * KPV + kgrp * 8;
    f32x4 acc[MT];
    for (int m = 0; m < MT; ++m)
        for (int r = 0; r < 4; ++r) acc[m][r] = 0.f;
    for (int k0 = 0; k0 < KPV; k0 += 32) {
        short8 b = *reinterpret_cast<const short8*>(bp + k0);
        #pragma unroll
        for (int m = 0; m < MT; ++m) {
            short8 a = *reinterpret_cast<const short8*>(ap + (size_t)m * 16 * KPV + k0);
            acc[m] = __builtin_amdgcn_mfma_f32_16x16x32_bf16(a, b, acc[m], 0, 0, 0);
        }
    }
    for (int m = 0; m < MT; ++m)
        for (int r = 0; r < 4; ++r) {
            int row = m * 16 + kgrp * 4 + r;
            if (row < NROW) out[(size_t)row * DD + ncol] = acc[m][r];
        }
}

extern "C" void kernel_launch(void* const* d_in, const int* in_sizes, int n_in,
                              void* d_out, int out_size, void* d_ws, size_t ws_size,
                              hipStream_t stream) {
    const float* x  = (const float*)d_in[0];
    const float* Wq = (const float*)d_in[1];
    const float* bq = (const float*)d_in[2];
    const float* Wk = (const float*)d_in[3];
    const float* bk = (const float*)d_in[4];
    const float* Wv = (const float*)d_in[5];
    const float* bv = (const float*)d_in[6];
    float* out = (float*)d_out;

    char* ws = (char*)d_ws;
    ushort* xb   = (ushort*)(ws);                       // 208*8192*2 = 3,407,872
    ushort* qb   = (ushort*)(ws + 3407872);             // 3,407,872
    ushort* kb   = (ushort*)(ws + 6815744);             // 3,407,872
    float*  vf   = (float*)(ws + 10223616);             // 200*8192*4 = 6,553,600
    ushort* vt   = (ushort*)(ws + 16777216);            // 8192*256*2 = 4,194,304
    float*  sbuf = (float*)(ws + 20971520);             // 208*208*4 = 173,056
    ushort* pb   = (ushort*)(ws + 21144576);            // 208*256*2 = 106,496
    // total 21,251,072 bytes

    cvt_x<<<832, 256, 0, stream>>>(x, xb);
    qkv_gemm<<<dim3(512, 3), 64, 0, stream>>>(xb, Wq, Wk, Wv, bq, bk, bv, qb, kb, vf);
    vtrans<<<dim3(128, 4), 256, 0, stream>>>(vf, vt);
    sgemm<<<dim3(13, 13), 256, 0, stream>>>(qb, kb, sbuf);
    rownorm<<<208, 256, 0, stream>>>(sbuf, pb);
    pv_gemm<<<128, 256, 0, stream>>>(pb, vt, out);
}

// Round 3
// 327.256 us; speedup vs baseline: 2.9688x; 2.6089x over previous
//
#include <hip/hip_runtime.h>
#include <hip/hip_bf16.h>
#include <cstdint>

#define DD 8192
#define NROW 200
#define MT 13          // 13 M-tiles of 16 rows = 208
#define MPAD 208
#define KPV 256        // padded K for the PV GEMM
#define EPSV 1e-5f
#define BK 64
#define ABUF_BYTES (MPAD * BK * 2)   // 26624 bytes per LDS A-buffer

using short8 = __attribute__((ext_vector_type(8))) short;
using f32x4  = __attribute__((ext_vector_type(4))) float;

__device__ __forceinline__ ushort f2bf(float f) {
    union { float f; unsigned u; } c; c.f = f;
    unsigned u = c.u;
    return (ushort)((u + 0x7FFFu + ((u >> 16) & 1u)) >> 16);  // RNE
}

__device__ __forceinline__ short8 pack8(float4 a, float4 b) {
    short8 o;
    o[0]=f2bf(a.x); o[1]=f2bf(a.y); o[2]=f2bf(a.z); o[3]=f2bf(a.w);
    o[4]=f2bf(b.x); o[5]=f2bf(b.y); o[6]=f2bf(b.z); o[7]=f2bf(b.w);
    return o;
}

// ---------------- kernel 1: x (f32 [200][8192]) -> xb (bf16 [208][8192], pad rows 0)
__global__ void cvt_x(const float* __restrict__ x, ushort* __restrict__ xb) {
    int i = (blockIdx.x * 256 + threadIdx.x) * 8;
    int row = i >> 13;
    int col = i & (DD - 1);
    short8 o;
    if (row < NROW) {
        const float4* p = reinterpret_cast<const float4*>(x + (size_t)row * DD + col);
        float4 a = p[0], b = p[1];
        o = pack8(a, b);
    } else {
        for (int j = 0; j < 8; ++j) o[j] = 0;
    }
    *reinterpret_cast<short8*>(xb + i) = o;
}

// ---------------- kernel 2: fused QKV GEMM.  C = x @ W^T + b
// grid (256, 3), block 128 (2 waves). Block owns 32 N-cols (wave: 16), all 208 M-rows.
// A k-slice [208][64] bf16 double-buffered in LDS (global_load_lds, swizzled source);
// W register-double-buffered. 2-phase pipeline, one barrier per K-step.
// mat 0 -> qb (bf16), mat 1 -> kb (bf16), mat 2 -> vt transposed (bf16 [8192][KPV]).
__global__ __launch_bounds__(128) void qkv_gemm(
    const ushort* __restrict__ xb,
    const float* __restrict__ Wq, const float* __restrict__ Wk, const float* __restrict__ Wv,
    const float* __restrict__ bq, const float* __restrict__ bk, const float* __restrict__ bv,
    ushort* __restrict__ qb, ushort* __restrict__ kb, ushort* __restrict__ vt)
{
    __shared__ char Asm[2 * ABUF_BYTES];   // 53,248 B -> 3 blocks/CU

    const int mat = blockIdx.y;
    const float* W    = (mat == 0) ? Wq : (mat == 1 ? Wk : Wv);
    const float* bias = (mat == 0) ? bq : (mat == 1 ? bk : bv);

    const int t     = threadIdx.x;
    const int lane  = t & 63;
    const int wave  = t >> 6;
    const int col16 = lane & 15;
    const int kgrp  = lane >> 4;
    const int ncol  = blockIdx.x * 32 + wave * 16 + col16;

    const float* wp = W + (size_t)ncol * DD + kgrp * 8;

    // Staging: thread t writes LDS bytes [r*2048 + t*16, +16) (linear, gl_lds order).
    // Desired swizzled content at (row, slot): k-slot = slot ^ (row&7).
    // row = r*16 + (t>>3), slot = t&7  ->  kslot = (t&7) ^ ((t>>3)&7)  (r-independent).
    const ushort* sbase = xb + (size_t)(t >> 3) * DD + (size_t)(((t & 7) ^ ((t >> 3) & 7)) * 8);
    char* dbase = Asm + wave * 1024;

    // ds_read: a-frag for (m, chunk c): row = m*16+col16, slot = (c*4+kgrp) ^ (col16&7)
    const int b0off = col16 * 128 + ((kgrp ^ (col16 & 7)) * 16);
    const int b1off = b0off ^ 64;

    f32x4 acc[MT];
    #pragma unroll
    for (int m = 0; m < MT; ++m)
        for (int r = 0; r < 4; ++r) acc[m][r] = 0.f;

#define STAGE(B, KK) { _Pragma("unroll") for (int r = 0; r < 13; ++r) { \
        __builtin_amdgcn_global_load_lds( \
            (const __attribute__((address_space(1))) void*)(sbase + (KK) + r * 16 * DD), \
            (__attribute__((address_space(3))) void*)(dbase + (B) * ABUF_BYTES + r * 2048), \
            16, 0, 0); } }

#define LOADW(d0, d1, d2, d3, KK) { \
        d0 = *reinterpret_cast<const float4*>(wp + (KK)); \
        d1 = *reinterpret_cast<const float4*>(wp + (KK) + 4); \
        d2 = *reinterpret_cast<const float4*>(wp + (KK) + 32); \
        d3 = *reinterpret_cast<const float4*>(wp + (KK) + 36); }

#define COMPUTE(BASE, w0, w1, w2, w3) { \
        short8 bb0 = pack8(w0, w1); \
        short8 bb1 = pack8(w2, w3); \
        _Pragma("unroll") for (int m = 0; m < MT; ++m) { \
            short8 a0 = *reinterpret_cast<const short8*>(Asm + (BASE) + b0off + m * 2048); \
            acc[m] = __builtin_amdgcn_mfma_f32_16x16x32_bf16(a0, bb0, acc[m], 0, 0, 0); \
            short8 a1 = *reinterpret_cast<const short8*>(Asm + (BASE) + b1off + m * 2048); \
            acc[m] = __builtin_amdgcn_mfma_f32_16x16x32_bf16(a1, bb1, acc[m], 0, 0, 0); } }

    float4 wA0, wA1, wA2, wA3, wB0, wB1, wB2, wB3;

    STAGE(0, 0);
    LOADW(wA0, wA1, wA2, wA3, 0);
    __syncthreads();                       // drains vmcnt: buf0 + wA ready

    int k0 = 0;
    for (int it = 0; it < DD / BK; it += 2) {
        int kn1 = k0 + BK;                 // <= 8128, always in range
        STAGE(1, kn1);
        LOADW(wB0, wB1, wB2, wB3, kn1);
        COMPUTE(0, wA0, wA1, wA2, wA3);
        __syncthreads();

        int kn2 = (k0 + 2 * BK) & (DD - 1);  // wraps on last iter (dead prefetch)
        STAGE(0, kn2);
        LOADW(wA0, wA1, wA2, wA3, kn2);
        COMPUTE(ABUF_BYTES, wB0, wB1, wB2, wB3);
        __syncthreads();

        k0 += 2 * BK;
    }
#undef STAGE
#undef LOADW
#undef COMPUTE

    const float badd = bias[ncol];
    if (mat < 2) {
        ushort* outb = (mat == 0) ? qb : kb;
        #pragma unroll
        for (int m = 0; m < MT; ++m)
            for (int r = 0; r < 4; ++r) {
                int row = m * 16 + kgrp * 4 + r;   // C/D: col=lane&15, row=(lane>>4)*4+r
                outb[(size_t)row * DD + ncol] = f2bf(acc[m][r] + badd);
            }
    } else {
        // write V directly transposed: vt[n][k] = v[k][n], bf16
        #pragma unroll
        for (int m = 0; m < MT; ++m)
            for (int r = 0; r < 4; ++r) {
                int row = m * 16 + kgrp * 4 + r;
                vt[(size_t)ncol * KPV + row] = f2bf(acc[m][r] + badd);
            }
    }
}

// ---------------- kernel 4: s = q @ k^T  (f32 [208][208]); grid (13,13), 4-wave K-split
__global__ __launch_bounds__(256) void sgemm(const ushort* __restrict__ qb, const ushort* __restrict__ kb,
                                             float* __restrict__ sbuf) {
    const int bm = blockIdx.y, bn = blockIdx.x;
    const int lane  = threadIdx.x & 63;
    const int wave  = threadIdx.x >> 6;
    const int col16 = lane & 15, kgrp = lane >> 4;
    const ushort* ap = qb + (size_t)(bm * 16 + col16) * DD + kgrp * 8;
    const ushort* bp = kb + (size_t)(bn * 16 + col16) * DD + kgrp * 8;
    f32x4 acc;
    for (int r = 0; r < 4; ++r) acc[r] = 0.f;
    const int kend = (wave + 1) * 2048;
    for (int k0 = wave * 2048; k0 < kend; k0 += 32) {
        short8 a = *reinterpret_cast<const short8*>(ap + k0);
        short8 b = *reinterpret_cast<const short8*>(bp + k0);
        acc = __builtin_amdgcn_mfma_f32_16x16x32_bf16(a, b, acc, 0, 0, 0);
    }
    __shared__ f32x4 red[4][64];
    red[wave][lane] = acc;
    __syncthreads();
    if (wave == 0) {
        f32x4 s = red[0][lane];
        for (int j = 1; j < 4; ++j) { f32x4 o = red[j][lane]; for (int r = 0; r < 4; ++r) s[r] += o[r]; }
        for (int r = 0; r < 4; ++r)
            sbuf[(size_t)(bm * 16 + kgrp * 4 + r) * MPAD + bn * 16 + col16] = s[r];
    }
}

// ---------------- kernel 5: per-row mean/var(ddof=1) -> sin -> softmax -> P bf16 [208][256] (pads 0)
__global__ __launch_bounds__(256) void rownorm(const float* __restrict__ sbuf, ushort* __restrict__ pb) {
    const int row = blockIdx.x;
    const int t = threadIdx.x;
    if (row >= NROW) { pb[(size_t)row * KPV + t] = 0; return; }
    __shared__ float part[4];
    const int lane = t & 63, wave = t >> 6;
    float x = (t < NROW) ? sbuf[(size_t)row * MPAD + t] : 0.f;

    float s = x;
    for (int m = 32; m; m >>= 1) s += __shfl_xor(s, m, 64);
    if (lane == 0) part[wave] = s;
    __syncthreads();
    float mean = (part[0] + part[1] + part[2] + part[3]) * (1.f / 200.f);

    float d = (t < NROW) ? (x - mean) : 0.f;
    float s2 = d * d;
    for (int m = 32; m; m >>= 1) s2 += __shfl_xor(s2, m, 64);
    __syncthreads();
    if (lane == 0) part[wave] = s2;
    __syncthreads();
    float var = (part[0] + part[1] + part[2] + part[3]) * (1.f / 199.f);

    float inv = 1.f / sqrtf(var + EPSV);
    float y = sinf(d * inv);
    const float inv_cc = 1.f / 90.50966799187809f;   // 1/sqrt(8192)
    float e = (t < NROW) ? expf(y * inv_cc) : 0.f;

    float se = e;
    for (int m = 32; m; m >>= 1) se += __shfl_xor(se, m, 64);
    __syncthreads();
    if (lane == 0) part[wave] = se;
    __syncthreads();
    float tot = part[0] + part[1] + part[2] + part[3];
    pb[(size_t)row * KPV + t] = (t < NROW) ? f2bf(e / tot) : (ushort)0;
}

// ---------------- kernel 6: out = P @ V  via out[m][n] = sum_k P[m][k] * vt[n][k]
__global__ __launch_bounds__(256) void pv_gemm(const ushort* __restrict__ pb, const ushort* __restrict__ vt,
                                               float* __restrict__ out) {
    const int lane  = threadIdx.x & 63;
    const int wave  = threadIdx.x >> 6;
    const int col16 = lane & 15, kgrp = lane >> 4;
    const int ncol  = blockIdx.x * 64 + wave * 16 + col16;
    const ushort* ap = pb + (size_t)col16 * KPV + kgrp * 8;
    const ushort* bp = vt + (size_t)ncol  * KPV + kgrp * 8;
    f32x4 acc[MT];
    for (int m = 0; m < MT; ++m)
        for (int r = 0; r < 4; ++r) acc[m][r] = 0.f;
    for (int k0 = 0; k0 < KPV; k0 += 32) {
        short8 b = *reinterpret_cast<const short8*>(bp + k0);
        #pragma unroll
        for (int m = 0; m < MT; ++m) {
            short8 a = *reinterpret_cast<const short8*>(ap + (size_t)m * 16 * KPV + k0);
            acc[m] = __builtin_amdgcn_mfma_f32_16x16x32_bf16(a, b, acc[m], 0, 0, 0);
        }
    }
    for (int m = 0; m < MT; ++m)
        for (int r = 0; r < 4; ++r) {
            int row = m * 16 + kgrp * 4 + r;
            if (row < NROW) out[(size_t)row * DD + ncol] = acc[m][r];
        }
}

extern "C" void kernel_launch(void* const* d_in, const int* in_sizes, int n_in,
                              void* d_out, int out_size, void* d_ws, size_t ws_size,
                              hipStream_t stream) {
    const float* x  = (const float*)d_in[0];
    const float* Wq = (const float*)d_in[1];
    const float* bq = (const float*)d_in[2];
    const float* Wk = (const float*)d_in[3];
    const float* bk = (const float*)d_in[4];
    const float* Wv = (const float*)d_in[5];
    const float* bv = (const float*)d_in[6];
    float* out = (float*)d_out;

    char* ws = (char*)d_ws;
    ushort* xb   = (ushort*)(ws);                       // 208*8192*2 = 3,407,872
    ushort* qb   = (ushort*)(ws + 3407872);             // 3,407,872
    ushort* kb   = (ushort*)(ws + 6815744);             // 3,407,872
    ushort* vt   = (ushort*)(ws + 10223616);            // 8192*256*2 = 4,194,304
    float*  sbuf = (float*)(ws + 14417920);             // 208*208*4 = 173,056
    ushort* pb   = (ushort*)(ws + 14590976);            // 208*256*2 = 106,496
    // total 14,697,472 bytes

    cvt_x<<<832, 256, 0, stream>>>(x, xb);
    qkv_gemm<<<dim3(256, 3), 128, 0, stream>>>(xb, Wq, Wk, Wv, bq, bk, bv, qb, kb, vt);
    sgemm<<<dim3(13, 13), 256, 0, stream>>>(qb, kb, sbuf);
    rownorm<<<208, 256, 0, stream>>>(sbuf, pb);
    pv_gemm<<<128, 256, 0, stream>>>(pb, vt, out);
}

// Round 4
// 295.409 us; speedup vs baseline: 3.2888x; 1.1078x over previous
//
#include <hip/hip_runtime.h>
#include <hip/hip_bf16.h>
#include <cstdint>

#define DD 8192
#define NROW 200
#define MT 13          // 13 M-tiles of 16 rows = 208
#define MPAD 208
#define KPV 256        // padded K for the PV GEMM
#define EPSV 1e-5f
#define BK 64
#define ABUF_BYTES (MPAD * BK * 2)   // 26624 bytes per LDS A-buffer

using short8 = __attribute__((ext_vector_type(8))) short;
using f32x4  = __attribute__((ext_vector_type(4))) float;

#define MEMBAR asm volatile("" ::: "memory")
#define RAWBAR asm volatile("s_barrier" ::: "memory")

__device__ __forceinline__ ushort f2bf(float f) {
    union { float f; unsigned u; } c; c.f = f;
    unsigned u = c.u;
    return (ushort)((u + 0x7FFFu + ((u >> 16) & 1u)) >> 16);  // RNE
}

__device__ __forceinline__ short8 pack8(float4 a, float4 b) {
    short8 o;
    o[0]=f2bf(a.x); o[1]=f2bf(a.y); o[2]=f2bf(a.z); o[3]=f2bf(a.w);
    o[4]=f2bf(b.x); o[5]=f2bf(b.y); o[6]=f2bf(b.z); o[7]=f2bf(b.w);
    return o;
}

// ---------------- kernel 1: x (f32 [200][8192]) -> xb (bf16 [208][8192], pad rows 0)
__global__ void cvt_x(const float* __restrict__ x, ushort* __restrict__ xb) {
    int i = (blockIdx.x * 256 + threadIdx.x) * 8;
    int row = i >> 13;
    int col = i & (DD - 1);
    short8 o;
    if (row < NROW) {
        const float4* p = reinterpret_cast<const float4*>(x + (size_t)row * DD + col);
        float4 a = p[0], b = p[1];
        o = pack8(a, b);
    } else {
        for (int j = 0; j < 8; ++j) o[j] = 0;
    }
    *reinterpret_cast<short8*>(xb + i) = o;
}

// ---------------- kernel 2: fused QKV GEMM.  C = x @ W^T + b
// grid (256, 3), block 128 (2 waves). Block owns 32 N-cols (wave: 16), all 208 M-rows.
// Counted-vmcnt pipeline (T3/T4): stage 1 K-step ahead into LDS dbuf, W-regs 2 K-steps
// ahead; raw s_barrier (no vmcnt(0) drain), explicit s_waitcnt vmcnt(21).
// mat 0 -> qb (bf16), mat 1 -> kb (bf16), mat 2 -> vt transposed (bf16 [8192][KPV]).
__global__ __launch_bounds__(128) void qkv_gemm(
    const ushort* __restrict__ xb,
    const float* __restrict__ Wq, const float* __restrict__ Wk, const float* __restrict__ Wv,
    const float* __restrict__ bq, const float* __restrict__ bk, const float* __restrict__ bv,
    ushort* __restrict__ qb, ushort* __restrict__ kb, ushort* __restrict__ vt)
{
    __shared__ char Asm[2 * ABUF_BYTES];   // 53,248 B -> 3 blocks/CU

    const int mat = blockIdx.y;
    const float* W    = (mat == 0) ? Wq : (mat == 1 ? Wk : Wv);
    const float* bias = (mat == 0) ? bq : (mat == 1 ? bk : bv);

    const int t     = threadIdx.x;
    const int lane  = t & 63;
    const int wave  = t >> 6;
    const int col16 = lane & 15;
    const int kgrp  = lane >> 4;
    const int ncol  = blockIdx.x * 32 + wave * 16 + col16;

    const float* wp = W + (size_t)ncol * DD + kgrp * 8;

    // Staging: thread t writes LDS bytes [r*2048 + t*16, +16) (linear, gl_lds order).
    // Swizzled content: k-slot = slot ^ (row&7); row = r*16 + (t>>3), slot = t&7.
    const ushort* sbase = xb + (size_t)(t >> 3) * DD + (size_t)(((t & 7) ^ ((t >> 3) & 7)) * 8);
    char* dbase = Asm + wave * 1024;

    // ds_read: a-frag for (m, chunk c): row = m*16+col16, slot = (c*4+kgrp) ^ (col16&7)
    const int b0off = col16 * 128 + ((kgrp ^ (col16 & 7)) * 16);
    const int b1off = b0off ^ 64;

    f32x4 acc[MT];
    #pragma unroll
    for (int m = 0; m < MT; ++m)
        for (int r = 0; r < 4; ++r) acc[m][r] = 0.f;

#define STAGE(B, KK) { _Pragma("unroll") for (int r = 0; r < 13; ++r) { \
        __builtin_amdgcn_global_load_lds( \
            (const __attribute__((address_space(1))) void*)(sbase + (KK) + r * 16 * DD), \
            (__attribute__((address_space(3))) void*)(dbase + (B) * ABUF_BYTES + r * 2048), \
            16, 0, 0); } }

#define LOADW(d0, d1, d2, d3, KK) { \
        d0 = *reinterpret_cast<const float4*>(wp + (KK)); \
        d1 = *reinterpret_cast<const float4*>(wp + (KK) + 4); \
        d2 = *reinterpret_cast<const float4*>(wp + (KK) + 32); \
        d3 = *reinterpret_cast<const float4*>(wp + (KK) + 36); }

#define COMPUTE(BASE, bb0, bb1) { \
        _Pragma("unroll") for (int m = 0; m < MT; ++m) { \
            short8 a0 = *reinterpret_cast<const short8*>(Asm + (BASE) + b0off + m * 2048); \
            acc[m] = __builtin_amdgcn_mfma_f32_16x16x32_bf16(a0, bb0, acc[m], 0, 0, 0); \
            short8 a1 = *reinterpret_cast<const short8*>(Asm + (BASE) + b1off + m * 2048); \
            acc[m] = __builtin_amdgcn_mfma_f32_16x16x32_bf16(a1, bb1, acc[m], 0, 0, 0); } }

    float4 wA0, wA1, wA2, wA3, wB0, wB1, wB2, wB3;

    // prologue: stage K0 into buf0; W(K0)->wA, W(K1)->wB
    STAGE(0, 0);
    MEMBAR;
    LOADW(wA0, wA1, wA2, wA3, 0);
    LOADW(wB0, wB1, wB2, wB3, BK);
    MEMBAR;

    for (int k0 = 0; k0 < DD; k0 += 2 * BK) {
        // ---- even phase: compute K=k0 from buf0 with wA
        {
            short8 bb0 = pack8(wA0, wA1);   // compiler auto-waits wA here
            short8 bb1 = pack8(wA2, wA3);
            STAGE(1, k0 + BK);              // stage K-step t+1
            MEMBAR;
            int kp = (k0 + 2 * BK) & (DD - 1);   // W for t+2 (wraps -> dead on last iter)
            LOADW(wA0, wA1, wA2, wA3, kp);
            MEMBAR;
            asm volatile("s_waitcnt vmcnt(21)" ::: "memory");
            RAWBAR;
            COMPUTE(0, bb0, bb1);
            RAWBAR;
        }
        // ---- odd phase: compute K=k0+BK from buf1 with wB
        {
            short8 bb0 = pack8(wB0, wB1);
            short8 bb1 = pack8(wB2, wB3);
            int kp1 = (k0 + 2 * BK) & (DD - 1);
            STAGE(0, kp1);
            MEMBAR;
            int kp2 = (k0 + 3 * BK) & (DD - 1);
            LOADW(wB0, wB1, wB2, wB3, kp2);
            MEMBAR;
            asm volatile("s_waitcnt vmcnt(21)" ::: "memory");
            RAWBAR;
            COMPUTE(ABUF_BYTES, bb0, bb1);
            RAWBAR;
        }
    }
#undef STAGE
#undef LOADW
#undef COMPUTE

    const float badd = bias[ncol];
    if (mat < 2) {
        ushort* outb = (mat == 0) ? qb : kb;
        #pragma unroll
        for (int m = 0; m < MT; ++m)
            for (int r = 0; r < 4; ++r) {
                int row = m * 16 + kgrp * 4 + r;   // C/D: col=lane&15, row=(lane>>4)*4+r
                outb[(size_t)row * DD + ncol] = f2bf(acc[m][r] + badd);
            }
    } else {
        // write V directly transposed: vt[n][k] = v[k][n], bf16
        #pragma unroll
        for (int m = 0; m < MT; ++m)
            for (int r = 0; r < 4; ++r) {
                int row = m * 16 + kgrp * 4 + r;
                vt[(size_t)ncol * KPV + row] = f2bf(acc[m][r] + badd);
            }
    }
}

// ---------------- kernel 4: s = q @ k^T  (f32 [208][208]); grid (13,13), 4-wave K-split
__global__ __launch_bounds__(256) void sgemm(const ushort* __restrict__ qb, const ushort* __restrict__ kb,
                                             float* __restrict__ sbuf) {
    const int bm = blockIdx.y, bn = blockIdx.x;
    const int lane  = threadIdx.x & 63;
    const int wave  = threadIdx.x >> 6;
    const int col16 = lane & 15, kgrp = lane >> 4;
    const ushort* ap = qb + (size_t)(bm * 16 + col16) * DD + kgrp * 8;
    const ushort* bp = kb + (size_t)(bn * 16 + col16) * DD + kgrp * 8;
    f32x4 acc;
    for (int r = 0; r < 4; ++r) acc[r] = 0.f;
    const int kend = (wave + 1) * 2048;
    for (int k0 = wave * 2048; k0 < kend; k0 += 32) {
        short8 a = *reinterpret_cast<const short8*>(ap + k0);
        short8 b = *reinterpret_cast<const short8*>(bp + k0);
        acc = __builtin_amdgcn_mfma_f32_16x16x32_bf16(a, b, acc, 0, 0, 0);
    }
    __shared__ f32x4 red[4][64];
    red[wave][lane] = acc;
    __syncthreads();
    if (wave == 0) {
        f32x4 s = red[0][lane];
        for (int j = 1; j < 4; ++j) { f32x4 o = red[j][lane]; for (int r = 0; r < 4; ++r) s[r] += o[r]; }
        for (int r = 0; r < 4; ++r)
            sbuf[(size_t)(bm * 16 + kgrp * 4 + r) * MPAD + bn * 16 + col16] = s[r];
    }
}

// ---------------- kernel 5: per-row mean/var(ddof=1) -> sin -> softmax -> P bf16 [208][256] (pads 0)
__global__ __launch_bounds__(256) void rownorm(const float* __restrict__ sbuf, ushort* __restrict__ pb) {
    const int row = blockIdx.x;
    const int t = threadIdx.x;
    if (row >= NROW) { pb[(size_t)row * KPV + t] = 0; return; }
    __shared__ float part[4];
    const int lane = t & 63, wave = t >> 6;
    float x = (t < NROW) ? sbuf[(size_t)row * MPAD + t] : 0.f;

    float s = x;
    for (int m = 32; m; m >>= 1) s += __shfl_xor(s, m, 64);
    if (lane == 0) part[wave] = s;
    __syncthreads();
    float mean = (part[0] + part[1] + part[2] + part[3]) * (1.f / 200.f);

    float d = (t < NROW) ? (x - mean) : 0.f;
    float s2 = d * d;
    for (int m = 32; m; m >>= 1) s2 += __shfl_xor(s2, m, 64);
    __syncthreads();
    if (lane == 0) part[wave] = s2;
    __syncthreads();
    float var = (part[0] + part[1] + part[2] + part[3]) * (1.f / 199.f);

    float inv = 1.f / sqrtf(var + EPSV);
    float y = sinf(d * inv);
    const float inv_cc = 1.f / 90.50966799187809f;   // 1/sqrt(8192)
    float e = (t < NROW) ? expf(y * inv_cc) : 0.f;

    float se = e;
    for (int m = 32; m; m >>= 1) se += __shfl_xor(se, m, 64);
    __syncthreads();
    if (lane == 0) part[wave] = se;
    __syncthreads();
    float tot = part[0] + part[1] + part[2] + part[3];
    pb[(size_t)row * KPV + t] = (t < NROW) ? f2bf(e / tot) : (ushort)0;
}

// ---------------- kernel 6: out = P @ V  via out[m][n] = sum_k P[m][k] * vt[n][k]
__global__ __launch_bounds__(256) void pv_gemm(const ushort* __restrict__ pb, const ushort* __restrict__ vt,
                                               float* __restrict__ out) {
    const int lane  = threadIdx.x & 63;
    const int wave  = threadIdx.x >> 6;
    const int col16 = lane & 15, kgrp = lane >> 4;
    const int ncol  = blockIdx.x * 64 + wave * 16 + col16;
    const ushort* ap = pb + (size_t)col16 * KPV + kgrp * 8;
    const ushort* bp = vt + (size_t)ncol  * KPV + kgrp * 8;
    f32x4 acc[MT];
    for (int m = 0; m < MT; ++m)
        for (int r = 0; r < 4; ++r) acc[m][r] = 0.f;
    for (int k0 = 0; k0 < KPV; k0 += 32) {
        short8 b = *reinterpret_cast<const short8*>(bp + k0);
        #pragma unroll
        for (int m = 0; m < MT; ++m) {
            short8 a = *reinterpret_cast<const short8*>(ap + (size_t)m * 16 * KPV + k0);
            acc[m] = __builtin_amdgcn_mfma_f32_16x16x32_bf16(a, b, acc[m], 0, 0, 0);
        }
    }
    for (int m = 0; m < MT; ++m)
        for (int r = 0; r < 4; ++r) {
            int row = m * 16 + kgrp * 4 + r;
            if (row < NROW) out[(size_t)row * DD + ncol] = acc[m][r];
        }
}

extern "C" void kernel_launch(void* const* d_in, const int* in_sizes, int n_in,
                              void* d_out, int out_size, void* d_ws, size_t ws_size,
                              hipStream_t stream) {
    const float* x  = (const float*)d_in[0];
    const float* Wq = (const float*)d_in[1];
    const float* bq = (const float*)d_in[2];
    const float* Wk = (const float*)d_in[3];
    const float* bk = (const float*)d_in[4];
    const float* Wv = (const float*)d_in[5];
    const float* bv = (const float*)d_in[6];
    float* out = (float*)d_out;

    char* ws = (char*)d_ws;
    ushort* xb   = (ushort*)(ws);                       // 208*8192*2 = 3,407,872
    ushort* qb   = (ushort*)(ws + 3407872);             // 3,407,872
    ushort* kb   = (ushort*)(ws + 6815744);             // 3,407,872
    ushort* vt   = (ushort*)(ws + 10223616);            // 8192*256*2 = 4,194,304
    float*  sbuf = (float*)(ws + 14417920);             // 208*208*4 = 173,056
    ushort* pb   = (ushort*)(ws + 14590976);            // 208*256*2 = 106,496
    // total 14,697,472 bytes

    cvt_x<<<832, 256, 0, stream>>>(x, xb);
    qkv_gemm<<<dim3(256, 3), 128, 0, stream>>>(xb, Wq, Wk, Wv, bq, bk, bv, qb, kb, vt);
    sgemm<<<dim3(13, 13), 256, 0, stream>>>(qb, kb, sbuf);
    rownorm<<<208, 256, 0, stream>>>(sbuf, pb);
    pv_gemm<<<128, 256, 0, stream>>>(pb, vt, out);
}

// Round 5
// 284.192 us; speedup vs baseline: 3.4186x; 1.0395x over previous
//
#include <hip/hip_runtime.h>
#include <hip/hip_bf16.h>
#include <cstdint>

#define DD 8192
#define NROW 200
#define MT 13          // 13 M-tiles of 16 rows = 208
#define MPAD 208
#define KPV 256        // padded K for the PV GEMM
#define EPSV 1e-5f
#define BK 64
#define ABUF_BYTES (MPAD * BK * 2)   // 26624 bytes per LDS A-buffer

using short8 = __attribute__((ext_vector_type(8))) short;
using f32x4  = __attribute__((ext_vector_type(4))) float;

#define MEMBAR asm volatile("" ::: "memory")

__device__ __forceinline__ ushort f2bf(float f) {
    union { float f; unsigned u; } c; c.f = f;
    unsigned u = c.u;
    return (ushort)((u + 0x7FFFu + ((u >> 16) & 1u)) >> 16);  // RNE
}

__device__ __forceinline__ short8 pack8(float4 a, float4 b) {
    short8 o;
    o[0]=f2bf(a.x); o[1]=f2bf(a.y); o[2]=f2bf(a.z); o[3]=f2bf(a.w);
    o[4]=f2bf(b.x); o[5]=f2bf(b.y); o[6]=f2bf(b.z); o[7]=f2bf(b.w);
    return o;
}

// ---------------- kernel 1: x (f32 [200][8192]) -> xb (bf16 [208][8192], pad rows 0)
__global__ void cvt_x(const float* __restrict__ x, ushort* __restrict__ xb) {
    int i = (blockIdx.x * 256 + threadIdx.x) * 8;
    int row = i >> 13;
    int col = i & (DD - 1);
    short8 o;
    if (row < NROW) {
        const float4* p = reinterpret_cast<const float4*>(x + (size_t)row * DD + col);
        float4 a = p[0], b = p[1];
        o = pack8(a, b);
    } else {
        for (int j = 0; j < 8; ++j) o[j] = 0;
    }
    *reinterpret_cast<short8*>(xb + i) = o;
}

// ---------------- kernel 2: fused QKV GEMM.  C = x @ W^T + b
// grid (256, 3), block 64 (1 wave -> NO barriers). Wave owns 32 N-cols (2 col-groups),
// all 208 M-rows: each A ds_read feeds 2 MFMAs (halves LDS read amplification).
// A k-slice [208][64] bf16 double-buffered in LDS (gl_lds, swizzled source), staged
// 1 phase ahead; W register-double-buffered 2 phases ahead; counted s_waitcnt vmcnt(42).
// 3 blocks/CU (LDS 3x53248 = 159744 <= 160 KiB exact fit).
__global__ __launch_bounds__(64) void qkv_gemm(
    const ushort* __restrict__ xb,
    const float* __restrict__ Wq, const float* __restrict__ Wk, const float* __restrict__ Wv,
    const float* __restrict__ bq, const float* __restrict__ bk, const float* __restrict__ bv,
    ushort* __restrict__ qb, ushort* __restrict__ kb, ushort* __restrict__ vt)
{
    __shared__ char Asm[2 * ABUF_BYTES];   // 53,248 B

    const int mat = blockIdx.y;
    const float* W    = (mat == 0) ? Wq : (mat == 1 ? Wk : Wv);
    const float* bias = (mat == 0) ? bq : (mat == 1 ? bk : bv);

    const int lane  = threadIdx.x;       // 0..63
    const int col16 = lane & 15;
    const int kgrp  = lane >> 4;
    const int ncol0 = blockIdx.x * 32 + col16;
    const int ncol1 = ncol0 + 16;

    const float* wp0 = W + (size_t)ncol0 * DD + kgrp * 8;
    const float* wp1 = W + (size_t)ncol1 * DD + kgrp * 8;

    // Staging (64 lanes x 16B = 1KB = 8 rows per gl_lds; 26 per 208x64 slice).
    // Linear LDS dest; swizzled GLOBAL source so content at (row, slot16B) holds
    // k-slot = slot ^ (row&7):  row = r*8 + (lane>>3), slot = lane&7.
    const ushort* sbase = xb + (size_t)(lane >> 3) * DD
                             + (size_t)(((lane & 7) ^ ((lane >> 3) & 7)) * 8);

    // ds_read: a-frag (m, chunk c): row = m*16+col16, slot = (c*4+kgrp) ^ (col16&7)
    const int b0off = col16 * 128 + ((kgrp ^ (col16 & 7)) * 16);
    const int b1off = b0off ^ 64;

    f32x4 acc0[MT], acc1[MT];
    #pragma unroll
    for (int m = 0; m < MT; ++m)
        for (int r = 0; r < 4; ++r) { acc0[m][r] = 0.f; acc1[m][r] = 0.f; }

#define STAGE(B, KK) { _Pragma("unroll") for (int r = 0; r < 26; ++r) { \
        __builtin_amdgcn_global_load_lds( \
            (const __attribute__((address_space(1))) void*)(sbase + (KK) + r * 8 * DD), \
            (__attribute__((address_space(3))) void*)(Asm + (B) * ABUF_BYTES + r * 1024), \
            16, 0, 0); } }

#define LOADW(d, KK) { \
        d##0 = *reinterpret_cast<const float4*>(wp0 + (KK)); \
        d##1 = *reinterpret_cast<const float4*>(wp0 + (KK) + 4); \
        d##2 = *reinterpret_cast<const float4*>(wp0 + (KK) + 32); \
        d##3 = *reinterpret_cast<const float4*>(wp0 + (KK) + 36); \
        d##4 = *reinterpret_cast<const float4*>(wp1 + (KK)); \
        d##5 = *reinterpret_cast<const float4*>(wp1 + (KK) + 4); \
        d##6 = *reinterpret_cast<const float4*>(wp1 + (KK) + 32); \
        d##7 = *reinterpret_cast<const float4*>(wp1 + (KK) + 36); }

#define COMPUTE(BASE, b00, b01, b10, b11) { \
        _Pragma("unroll") for (int m = 0; m < MT; ++m) { \
            short8 a0 = *reinterpret_cast<const short8*>(Asm + (BASE) + b0off + m * 2048); \
            acc0[m] = __builtin_amdgcn_mfma_f32_16x16x32_bf16(a0, b00, acc0[m], 0, 0, 0); \
            acc1[m] = __builtin_amdgcn_mfma_f32_16x16x32_bf16(a0, b10, acc1[m], 0, 0, 0); \
            short8 a1 = *reinterpret_cast<const short8*>(Asm + (BASE) + b1off + m * 2048); \
            acc0[m] = __builtin_amdgcn_mfma_f32_16x16x32_bf16(a1, b01, acc0[m], 0, 0, 0); \
            acc1[m] = __builtin_amdgcn_mfma_f32_16x16x32_bf16(a1, b11, acc1[m], 0, 0, 0); } }

    float4 wA0, wA1, wA2, wA3, wA4, wA5, wA6, wA7;
    float4 wB0, wB1, wB2, wB3, wB4, wB5, wB6, wB7;

    // prologue: stage K0 into buf0; W(K0)->wA, W(K1)->wB
    STAGE(0, 0);
    MEMBAR;
    LOADW(wA, 0);
    MEMBAR;
    LOADW(wB, BK);
    MEMBAR;

    for (int k0 = 0; k0 < DD; k0 += 2 * BK) {
        // ---- even phase: compute K=k0 from buf0 with wA
        {
            short8 b00 = pack8(wA0, wA1);   // compiler auto-waits wA regs here
            short8 b01 = pack8(wA2, wA3);
            short8 b10 = pack8(wA4, wA5);
            short8 b11 = pack8(wA6, wA7);
            STAGE(1, k0 + BK);              // stage K-step t+1 (<= 8128, in range)
            MEMBAR;
            int kp = (k0 + 2 * BK) & (DD - 1);   // W for t+2 (wraps -> dead on last iter)
            LOADW(wA, kp);
            MEMBAR;
            asm volatile("s_waitcnt vmcnt(42)" ::: "memory");  // stage(t) complete
            COMPUTE(0, b00, b01, b10, b11);
        }
        // ---- odd phase: compute K=k0+BK from buf1 with wB
        {
            short8 b00 = pack8(wB0, wB1);
            short8 b01 = pack8(wB2, wB3);
            short8 b10 = pack8(wB4, wB5);
            short8 b11 = pack8(wB6, wB7);
            int kp1 = (k0 + 2 * BK) & (DD - 1);
            STAGE(0, kp1);
            MEMBAR;
            int kp2 = (k0 + 3 * BK) & (DD - 1);
            LOADW(wB, kp2);
            MEMBAR;
            asm volatile("s_waitcnt vmcnt(42)" ::: "memory");
            COMPUTE(ABUF_BYTES, b00, b01, b10, b11);
        }
    }
#undef STAGE
#undef LOADW
#undef COMPUTE

    const float badd0 = bias[ncol0];
    const float badd1 = bias[ncol1];
    if (mat < 2) {
        ushort* outb = (mat == 0) ? qb : kb;
        #pragma unroll
        for (int m = 0; m < MT; ++m)
            for (int r = 0; r < 4; ++r) {
                int row = m * 16 + kgrp * 4 + r;   // C/D: col=lane&15, row=(lane>>4)*4+r
                outb[(size_t)row * DD + ncol0] = f2bf(acc0[m][r] + badd0);
                outb[(size_t)row * DD + ncol1] = f2bf(acc1[m][r] + badd1);
            }
    } else {
        // write V directly transposed: vt[n][k] = v[k][n], bf16
        #pragma unroll
        for (int m = 0; m < MT; ++m)
            for (int r = 0; r < 4; ++r) {
                int row = m * 16 + kgrp * 4 + r;
                vt[(size_t)ncol0 * KPV + row] = f2bf(acc0[m][r] + badd0);
                vt[(size_t)ncol1 * KPV + row] = f2bf(acc1[m][r] + badd1);
            }
    }
}

// ---------------- kernel 4: s = q @ k^T  (f32 [208][208]); grid (13,13), 4-wave K-split
__global__ __launch_bounds__(256) void sgemm(const ushort* __restrict__ qb, const ushort* __restrict__ kb,
                                             float* __restrict__ sbuf) {
    const int bm = blockIdx.y, bn = blockIdx.x;
    const int lane  = threadIdx.x & 63;
    const int wave  = threadIdx.x >> 6;
    const int col16 = lane & 15, kgrp = lane >> 4;
    const ushort* ap = qb + (size_t)(bm * 16 + col16) * DD + kgrp * 8;
    const ushort* bp = kb + (size_t)(bn * 16 + col16) * DD + kgrp * 8;
    f32x4 acc;
    for (int r = 0; r < 4; ++r) acc[r] = 0.f;
    const int kend = (wave + 1) * 2048;
    for (int k0 = wave * 2048; k0 < kend; k0 += 32) {
        short8 a = *reinterpret_cast<const short8*>(ap + k0);
        short8 b = *reinterpret_cast<const short8*>(bp + k0);
        acc = __builtin_amdgcn_mfma_f32_16x16x32_bf16(a, b, acc, 0, 0, 0);
    }
    __shared__ f32x4 red[4][64];
    red[wave][lane] = acc;
    __syncthreads();
    if (wave == 0) {
        f32x4 s = red[0][lane];
        for (int j = 1; j < 4; ++j) { f32x4 o = red[j][lane]; for (int r = 0; r < 4; ++r) s[r] += o[r]; }
        for (int r = 0; r < 4; ++r)
            sbuf[(size_t)(bm * 16 + kgrp * 4 + r) * MPAD + bn * 16 + col16] = s[r];
    }
}

// ---------------- kernel 5: per-row mean/var(ddof=1) -> sin -> softmax -> P bf16 [208][256] (pads 0)
__global__ __launch_bounds__(256) void rownorm(const float* __restrict__ sbuf, ushort* __restrict__ pb) {
    const int row = blockIdx.x;
    const int t = threadIdx.x;
    if (row >= NROW) { pb[(size_t)row * KPV + t] = 0; return; }
    __shared__ float part[4];
    const int lane = t & 63, wave = t >> 6;
    float x = (t < NROW) ? sbuf[(size_t)row * MPAD + t] : 0.f;

    float s = x;
    for (int m = 32; m; m >>= 1) s += __shfl_xor(s, m, 64);
    if (lane == 0) part[wave] = s;
    __syncthreads();
    float mean = (part[0] + part[1] + part[2] + part[3]) * (1.f / 200.f);

    float d = (t < NROW) ? (x - mean) : 0.f;
    float s2 = d * d;
    for (int m = 32; m; m >>= 1) s2 += __shfl_xor(s2, m, 64);
    __syncthreads();
    if (lane == 0) part[wave] = s2;
    __syncthreads();
    float var = (part[0] + part[1] + part[2] + part[3]) * (1.f / 199.f);

    float inv = 1.f / sqrtf(var + EPSV);
    float y = sinf(d * inv);
    const float inv_cc = 1.f / 90.50966799187809f;   // 1/sqrt(8192)
    float e = (t < NROW) ? expf(y * inv_cc) : 0.f;

    float se = e;
    for (int m = 32; m; m >>= 1) se += __shfl_xor(se, m, 64);
    __syncthreads();
    if (lane == 0) part[wave] = se;
    __syncthreads();
    float tot = part[0] + part[1] + part[2] + part[3];
    pb[(size_t)row * KPV + t] = (t < NROW) ? f2bf(e / tot) : (ushort)0;
}

// ---------------- kernel 6: out = P @ V  via out[m][n] = sum_k P[m][k] * vt[n][k]
__global__ __launch_bounds__(256) void pv_gemm(const ushort* __restrict__ pb, const ushort* __restrict__ vt,
                                               float* __restrict__ out) {
    const int lane  = threadIdx.x & 63;
    const int wave  = threadIdx.x >> 6;
    const int col16 = lane & 15, kgrp = lane >> 4;
    const int ncol  = blockIdx.x * 64 + wave * 16 + col16;
    const ushort* ap = pb + (size_t)col16 * KPV + kgrp * 8;
    const ushort* bp = vt + (size_t)ncol  * KPV + kgrp * 8;
    f32x4 acc[MT];
    for (int m = 0; m < MT; ++m)
        for (int r = 0; r < 4; ++r) acc[m][r] = 0.f;
    for (int k0 = 0; k0 < KPV; k0 += 32) {
        short8 b = *reinterpret_cast<const short8*>(bp + k0);
        #pragma unroll
        for (int m = 0; m < MT; ++m) {
            short8 a = *reinterpret_cast<const short8*>(ap + (size_t)m * 16 * KPV + k0);
            acc[m] = __builtin_amdgcn_mfma_f32_16x16x32_bf16(a, b, acc[m], 0, 0, 0);
        }
    }
    for (int m = 0; m < MT; ++m)
        for (int r = 0; r < 4; ++r) {
            int row = m * 16 + kgrp * 4 + r;
            if (row < NROW) out[(size_t)row * DD + ncol] = acc[m][r];
        }
}

extern "C" void kernel_launch(void* const* d_in, const int* in_sizes, int n_in,
                              void* d_out, int out_size, void* d_ws, size_t ws_size,
                              hipStream_t stream) {
    const float* x  = (const float*)d_in[0];
    const float* Wq = (const float*)d_in[1];
    const float* bq = (const float*)d_in[2];
    const float* Wk = (const float*)d_in[3];
    const float* bk = (const float*)d_in[4];
    const float* Wv = (const float*)d_in[5];
    const float* bv = (const float*)d_in[6];
    float* out = (float*)d_out;

    char* ws = (char*)d_ws;
    ushort* xb   = (ushort*)(ws);                       // 208*8192*2 = 3,407,872
    ushort* qb   = (ushort*)(ws + 3407872);             // 3,407,872
    ushort* kb   = (ushort*)(ws + 6815744);             // 3,407,872
    ushort* vt   = (ushort*)(ws + 10223616);            // 8192*256*2 = 4,194,304
    float*  sbuf = (float*)(ws + 14417920);             // 208*208*4 = 173,056
    ushort* pb   = (ushort*)(ws + 14590976);            // 208*256*2 = 106,496
    // total 14,697,472 bytes

    cvt_x<<<832, 256, 0, stream>>>(x, xb);
    qkv_gemm<<<dim3(256, 3), 64, 0, stream>>>(xb, Wq, Wk, Wv, bq, bk, bv, qb, kb, vt);
    sgemm<<<dim3(13, 13), 256, 0, stream>>>(qb, kb, sbuf);
    rownorm<<<208, 256, 0, stream>>>(sbuf, pb);
    pv_gemm<<<128, 256, 0, stream>>>(pb, vt, out);
}